// Round 1
// baseline (241.670 us; speedup 1.0000x reference)
//
#include <hip/hip_runtime.h>

// Problem constants (from reference): x [B=1,T=8,C=32,D=32,H=64,W=64] fp32
constexpr int NT = 8;    // B*T
constexpr int C  = 32;
constexpr int D  = 32;
constexpr int H  = 64;
constexpr int W  = 64;
constexpr int HT = 8;    // H rows per block in kernel A
constexpr int SP = D * H * W;       // per-channel spatial size = 131072

// ---------------------------------------------------------------------------
// Kernel A: fused depthwise chain
//   h = dwconv_z3(x)+b0z ; h = dwconv_x3(h)+b0x ; h = dwconv_y3(h)+b0y ;
//   3x: h = dwconv_z5_dil2(h)+bsz
// Output written to hdw (= d_out, later transformed in place by kernel B).
// One block: (n, c, h-tile of HT rows). 512 threads, each owns one (h,w)
// column of all 32 D values in registers.
// ---------------------------------------------------------------------------
__global__ __launch_bounds__(512, 1)
void dw_chain(const float* __restrict__ x,
              const float* __restrict__ w0z, const float* __restrict__ b0z,
              const float* __restrict__ w0x, const float* __restrict__ b0x,
              const float* __restrict__ w0y, const float* __restrict__ b0y,
              const float* __restrict__ wsz, const float* __restrict__ bsz,
              float* __restrict__ hdw)
{
    __shared__ float xs[D][HT + 2][W];   // 32*10*64*4 = 81920 B

    const int blk   = blockIdx.x;
    const int htile = blk % (H / HT);
    const int c     = (blk / (H / HT)) % C;
    const int n     = blk / ((H / HT) * C);
    const int h0    = htile * HT;
    const int tid   = threadIdx.x;

    const float* xc = x + ((size_t)n * C + c) * SP;

    // Cooperative load of [D][HT+2][W] tile, zero-padded in H.
    for (int i = tid; i < D * (HT + 2) * W; i += 512) {
        int w  = i % W;
        int hh = (i / W) % (HT + 2);
        int d  = i / (W * (HT + 2));
        int hg = h0 + hh - 1;
        float v = 0.f;
        if (hg >= 0 && hg < H) v = xc[(d * H + hg) * W + w];
        xs[d][hh][w] = v;
    }
    __syncthreads();

    const int w = tid % W;       // 0..63  (varies within wave)
    const int h = tid / W;       // 0..7   (wave-uniform)
    const int hg = h0 + h;

    // Per-channel weights (uniform across block -> SGPRs)
    const float wz0 = w0z[c * 3 + 0], wz1 = w0z[c * 3 + 1], wz2 = w0z[c * 3 + 2];
    const float wx0 = w0x[c * 3 + 0], wx1 = w0x[c * 3 + 1], wx2 = w0x[c * 3 + 2];
    const float wy0 = w0y[c * 3 + 0], wy1 = w0y[c * 3 + 1], wy2 = w0y[c * 3 + 2];
    const float bz = b0z[c], bx = b0x[c], by = b0y[c], bs = bsz[c];
    float wsk[5];
    #pragma unroll
    for (int k = 0; k < 5; ++k) wsk[k] = wsz[c * 5 + k];

    // acc3[d] = h3 column after the three 3-tap convs
    float acc3[D];
    #pragma unroll
    for (int d = 0; d < D; ++d) acc3[d] = by;

    #pragma unroll
    for (int dy = 0; dy < 3; ++dy) {
        const int wg = w + dy - 1;              // LDS w index == global w
        if (wg < 0 || wg >= W) continue;        // conv_y zero-pad: drop term incl. bias
        const float wyk = (dy == 0) ? wy0 : ((dy == 1) ? wy1 : wy2);

        float acc2[D];
        #pragma unroll
        for (int d = 0; d < D; ++d) acc2[d] = bx;

        #pragma unroll
        for (int dx = 0; dx < 3; ++dx) {
            const int hgg = hg + dx - 1;
            if (hgg < 0 || hgg >= H) continue;  // conv_x zero-pad: drop term incl. bias
            const int hh = h + dx;              // tile row
            const float wxk = (dx == 0) ? wx0 : ((dx == 1) ? wx1 : wx2);

            float xcol[D];
            #pragma unroll
            for (int d = 0; d < D; ++d) xcol[d] = xs[d][hh][wg];

            #pragma unroll
            for (int d = 0; d < D; ++d) {
                float t = bz;                   // conv_z bias always applied in-domain
                if (d > 0)     t += wz0 * xcol[d - 1];
                t += wz1 * xcol[d];
                if (d < D - 1) t += wz2 * xcol[d + 1];
                acc2[d] += wxk * t;
            }
        }
        #pragma unroll
        for (int d = 0; d < D; ++d) acc3[d] += wyk * acc2[d];
    }

    // Three applications of 5-tap dilation-2 conv along D (pad 4), in registers.
    #pragma unroll
    for (int it = 0; it < 3; ++it) {
        float s[D];
        #pragma unroll
        for (int d = 0; d < D; ++d) {
            float t = bs;
            #pragma unroll
            for (int k = 0; k < 5; ++k) {
                int j = d + 2 * k - 4;
                if (j >= 0 && j < D) t += wsk[k] * acc3[j];
            }
            s[d] = t;
        }
        #pragma unroll
        for (int d = 0; d < D; ++d) acc3[d] = s[d];
    }

    // Store column (coalesced across w per d)
    float* oc = hdw + ((size_t)n * C + c) * SP + (size_t)(h0 + h) * W + w;
    #pragma unroll
    for (int d = 0; d < D; ++d) oc[(size_t)d * H * W] = acc3[d];
}

// ---------------------------------------------------------------------------
// Kernel B: pointwise 1x1x1 conv over channels + residual multiply, IN PLACE
// on io (= d_out holding the depthwise-chain result).
//   out[c] = x[c] * (sum_ci wp[c][ci]*io[ci] + bp[c])
// One thread per spatial position owns all 32 channels -> in-place safe.
// ---------------------------------------------------------------------------
__global__ __launch_bounds__(256)
void pw_mul(const float* __restrict__ x,
            const float* __restrict__ wp, const float* __restrict__ bp,
            float* __restrict__ io)
{
    const size_t p = (size_t)blockIdx.x * 256 + threadIdx.x;  // (n, d, h, w)
    const size_t n  = p / SP;
    const size_t sp = p % SP;
    const size_t base = n * (size_t)C * SP + sp;

    float v[C];
    #pragma unroll
    for (int ci = 0; ci < C; ++ci) v[ci] = io[base + (size_t)ci * SP];

    for (int co = 0; co < C; ++co) {
        float y = bp[co];
        #pragma unroll
        for (int ci = 0; ci < C; ++ci) y += wp[co * C + ci] * v[ci];
        const size_t idx = base + (size_t)co * SP;
        io[idx] = x[idx] * y;
    }
}

extern "C" void kernel_launch(void* const* d_in, const int* in_sizes, int n_in,
                              void* d_out, int out_size, void* d_ws, size_t ws_size,
                              hipStream_t stream)
{
    const float* x   = (const float*)d_in[0];
    const float* w0z = (const float*)d_in[1];
    const float* b0z = (const float*)d_in[2];
    const float* w0x = (const float*)d_in[3];
    const float* b0x = (const float*)d_in[4];
    const float* w0y = (const float*)d_in[5];
    const float* b0y = (const float*)d_in[6];
    const float* wsz = (const float*)d_in[7];
    const float* bsz = (const float*)d_in[8];
    const float* wp  = (const float*)d_in[9];
    const float* bp  = (const float*)d_in[10];
    float* out = (float*)d_out;

    // Kernel A: depthwise chain -> d_out (scratch)
    const int gridA = NT * C * (H / HT);          // 8*32*8 = 2048
    dw_chain<<<gridA, 512, 0, stream>>>(x, w0z, b0z, w0x, b0x, w0y, b0y,
                                        wsz, bsz, out);

    // Kernel B: pointwise + residual, in place on d_out
    const int positions = NT * SP;                // 1,048,576
    pw_mul<<<positions / 256, 256, 0, stream>>>(x, wp, bp, out);
}

// Round 2
// 135.114 us; speedup vs baseline: 1.7886x; 1.7886x over previous
//
#include <hip/hip_runtime.h>

// Problem constants (from reference): x [B=1,T=8,C=32,D=32,H=64,W=64] fp32
constexpr int NT = 8;    // B*T
constexpr int C  = 32;
constexpr int D  = 32;
constexpr int H  = 64;
constexpr int W  = 64;   // == wavefront size: W-conv becomes lane shuffles
constexpr int ROWS = 4;  // h rows per block (one per wave)
constexpr int SP = D * H * W;       // per-channel spatial size = 131072

// ---------------------------------------------------------------------------
// Kernel A: fused depthwise chain, LDS-free.
//   h = dwconv_z3(x)+b0z ; h = dwconv_x3(h)+b0x ; h = dwconv_y3(h)+b0y ;
//   3x: h = dwconv_z5_dil2(h)+bsz
// One wave per (n,c,h) row; lane = w. Each thread owns the full D=32 column
// in registers. H-neighbors re-read from global (L1/L2 hits); W-neighbors via
// __shfl. Zero LDS, zero __syncthreads.
// Bias boundary semantics: when a tap of a later conv falls outside the
// image, the ENTIRE term (including the accumulated earlier biases) drops —
// handled by the skip-if-out-of-range logic, identical to round-1 kernel.
// ---------------------------------------------------------------------------
__global__ __launch_bounds__(256, 4)
void dw_chain(const float* __restrict__ x,
              const float* __restrict__ w0z, const float* __restrict__ b0z,
              const float* __restrict__ w0x, const float* __restrict__ b0x,
              const float* __restrict__ w0y, const float* __restrict__ b0y,
              const float* __restrict__ wsz, const float* __restrict__ bsz,
              float* __restrict__ hdw)
{
    const int blk   = blockIdx.x;
    const int htile = blk % (H / ROWS);
    const int c     = (blk / (H / ROWS)) % C;
    const int n     = blk / ((H / ROWS) * C);
    const int tid   = threadIdx.x;
    const int w     = tid & 63;            // lane
    const int hg    = htile * ROWS + (tid >> 6);

    const float* xc = x + ((size_t)n * C + c) * SP;

    // Per-channel weights (block-uniform -> scalar regs)
    const float wz0 = w0z[c * 3 + 0], wz1 = w0z[c * 3 + 1], wz2 = w0z[c * 3 + 2];
    const float wx0 = w0x[c * 3 + 0], wx1 = w0x[c * 3 + 1], wx2 = w0x[c * 3 + 2];
    const float wy0 = w0y[c * 3 + 0], wy1 = w0y[c * 3 + 1], wy2 = w0y[c * 3 + 2];
    const float bz = b0z[c], bx = b0x[c], by = b0y[c], bs = bsz[c];
    float wsk[5];
    #pragma unroll
    for (int k = 0; k < 5; ++k) wsk[k] = wsz[c * 5 + k];

    // Phase 1: acc2[d] = bx + sum_dx wx * zconv(x[:, hg+dx-1, w])
    float acc2[D];
    #pragma unroll
    for (int d = 0; d < D; ++d) acc2[d] = bx;

    #pragma unroll
    for (int dx = 0; dx < 3; ++dx) {
        const int hgg = hg + dx - 1;
        if (hgg < 0 || hgg >= H) continue;   // conv_x zero-pad: term (incl. bz) drops
        const float wxk = (dx == 0) ? wx0 : ((dx == 1) ? wx1 : wx2);

        float xcol[D];
        #pragma unroll
        for (int d = 0; d < D; ++d) xcol[d] = xc[(d * H + hgg) * W + w];

        #pragma unroll
        for (int d = 0; d < D; ++d) {
            float t = bz;                    // conv_z bias always applied in-domain
            if (d > 0)     t += wz0 * xcol[d - 1];
            t += wz1 * xcol[d];
            if (d < D - 1) t += wz2 * xcol[d + 1];
            acc2[d] += wxk * t;
        }
    }

    // Phase 2: W-direction 3-tap via lane shuffles (W == wavefront 64).
    // out(w) = by + wy0*in(w-1) + wy1*in(w) + wy2*in(w+1), boundary terms drop.
    const bool has_l = (w > 0), has_r = (w < W - 1);
    float acc3[D];
    #pragma unroll
    for (int d = 0; d < D; ++d) {
        float left  = __shfl_up(acc2[d], 1);     // value from lane w-1
        float right = __shfl_down(acc2[d], 1);   // value from lane w+1
        float t = by + wy1 * acc2[d];
        if (has_l) t += wy0 * left;
        if (has_r) t += wy2 * right;
        acc3[d] = t;
    }

    // Phase 3: three 5-tap dilation-2 convs along D (pad 4), in registers.
    #pragma unroll
    for (int it = 0; it < 3; ++it) {
        float s[D];
        #pragma unroll
        for (int d = 0; d < D; ++d) {
            float t = bs;
            #pragma unroll
            for (int k = 0; k < 5; ++k) {
                int j = d + 2 * k - 4;
                if (j >= 0 && j < D) t += wsk[k] * acc3[j];
            }
            s[d] = t;
        }
        #pragma unroll
        for (int d = 0; d < D; ++d) acc3[d] = s[d];
    }

    // Store column (coalesced across lanes per d)
    float* oc = hdw + ((size_t)n * C + c) * SP + (size_t)hg * W + w;
    #pragma unroll
    for (int d = 0; d < D; ++d) oc[(size_t)d * H * W] = acc3[d];
}

// ---------------------------------------------------------------------------
// Kernel B: pointwise 1x1x1 conv over channels + residual multiply, IN PLACE
// on io (= d_out holding the depthwise-chain result).
//   out[c] = x[c] * (sum_ci wp[c][ci]*io[ci] + bp[c])
// One thread per spatial position owns all 32 channels -> in-place safe.
// ---------------------------------------------------------------------------
__global__ __launch_bounds__(256)
void pw_mul(const float* __restrict__ x,
            const float* __restrict__ wp, const float* __restrict__ bp,
            float* __restrict__ io)
{
    const size_t p = (size_t)blockIdx.x * 256 + threadIdx.x;  // (n, d, h, w)
    const size_t n  = p / SP;
    const size_t sp = p % SP;
    const size_t base = n * (size_t)C * SP + sp;

    float v[C];
    #pragma unroll
    for (int ci = 0; ci < C; ++ci) v[ci] = io[base + (size_t)ci * SP];

    for (int co = 0; co < C; ++co) {
        float y = bp[co];
        #pragma unroll
        for (int ci = 0; ci < C; ++ci) y += wp[co * C + ci] * v[ci];
        const size_t idx = base + (size_t)co * SP;
        io[idx] = x[idx] * y;
    }
}

extern "C" void kernel_launch(void* const* d_in, const int* in_sizes, int n_in,
                              void* d_out, int out_size, void* d_ws, size_t ws_size,
                              hipStream_t stream)
{
    const float* x   = (const float*)d_in[0];
    const float* w0z = (const float*)d_in[1];
    const float* b0z = (const float*)d_in[2];
    const float* w0x = (const float*)d_in[3];
    const float* b0x = (const float*)d_in[4];
    const float* w0y = (const float*)d_in[5];
    const float* b0y = (const float*)d_in[6];
    const float* wsz = (const float*)d_in[7];
    const float* bsz = (const float*)d_in[8];
    const float* wp  = (const float*)d_in[9];
    const float* bp  = (const float*)d_in[10];
    float* out = (float*)d_out;

    // Kernel A: depthwise chain -> d_out (scratch)
    const int gridA = NT * C * (H / ROWS);        // 8*32*16 = 4096
    dw_chain<<<gridA, 256, 0, stream>>>(x, w0z, b0z, w0x, b0x, w0y, b0y,
                                        wsz, bsz, out);

    // Kernel B: pointwise + residual, in place on d_out
    const int positions = NT * SP;                // 1,048,576
    pw_mul<<<positions / 256, 256, 0, stream>>>(x, wp, bp, out);
}